// Round 11
// baseline (449.347 us; speedup 1.0000x reference)
//
#include <hip/hip_runtime.h>
#include <hip/hip_bf16.h>
#include <math.h>

// MoE MLP: T=8192 tokens, 8 experts, top-2, HID=1024, FFN=2048 (GLU).
// R11: gemm2 epilogue fused with gating -> atomicAdd into out (2 fp32 adds
// per element, commutative => bit-deterministic); y buffer + k_combine
// removed. gemm1/router/converts byte-identical to R10 (passed post-timing).

#define T_TOK 8192
#define HID   1024
#define NEXP  8
#define FFN   2048
#define PADU  256
#define MAXPAD (2 * T_TOK + NEXP * PADU) /* 18432 */
#define MTG1   (MAXPAD / 256)            /* 72 */
#define MTG2   (MAXPAD / 128)            /* 144 */

typedef __attribute__((ext_vector_type(4))) float f32x4;
typedef __attribute__((ext_vector_type(8))) short bf16x8;
typedef __attribute__((ext_vector_type(8))) unsigned short u16x8;

static __device__ __forceinline__ unsigned short f2bf(float f) {
  unsigned int u = __float_as_uint(f);
  u += 0x7fffu + ((u >> 16) & 1u);
  return (unsigned short)(u >> 16);
}
static __device__ __forceinline__ float bf2f(unsigned short h) {
  return __uint_as_float(((unsigned int)h) << 16);
}

#define GLDS16(gsrc, ldst)                                                  \
  __builtin_amdgcn_global_load_lds(                                        \
      (const __attribute__((address_space(1))) void*)(gsrc),               \
      (__attribute__((address_space(3))) void*)(ldst), 16, 0, 0)

#define SFENCE() __builtin_amdgcn_sched_barrier(0)
#define BARRIER() do { SFENCE(); __builtin_amdgcn_s_barrier(); SFENCE(); } while (0)
#define LGKM0() do { asm volatile("s_waitcnt lgkmcnt(0)" ::: "memory"); SFENCE(); } while (0)
#define VMW(n) asm volatile("s_waitcnt vmcnt(" #n ")" ::: "memory")

// ---------------- K1: router (fp64 acc, LDS wr^T, no atomics) --------------
__global__ __launch_bounds__(512) void k_router(
    const float* __restrict__ x, const float* __restrict__ wr,
    int* __restrict__ tok_idx, float* __restrict__ tok_gate) {
  __shared__ float wrT[8][1024];
  const int tid = threadIdx.x;
#pragma unroll
  for (int p = 0; p < 4; ++p) {
    const int idx = tid + p * 512;
    const float4 v = reinterpret_cast<const float4*>(wr)[idx];
    const int f = idx * 4;
    wrT[(f + 0) & 7][(f + 0) >> 3] = v.x;
    wrT[(f + 1) & 7][(f + 1) >> 3] = v.y;
    wrT[(f + 2) & 7][(f + 2) >> 3] = v.z;
    wrT[(f + 3) & 7][(f + 3) >> 3] = v.w;
  }
  __syncthreads();

  const int lane = tid & 63;
  const int wid  = tid >> 6;
  const int t    = blockIdx.x * 8 + wid;
  const float* xr = x + (size_t)t * HID;

  double acc[8] = {};
#pragma unroll
  for (int j = 0; j < 16; ++j) {
    const int k = lane + j * 64;
    const double xv = (double)xr[k];
#pragma unroll
    for (int e = 0; e < 8; ++e) acc[e] += xv * (double)wrT[e][k];
  }
#pragma unroll
  for (int e = 0; e < 8; ++e) {
#pragma unroll
    for (int off = 32; off > 0; off >>= 1) acc[e] += __shfl_down(acc[e], off);
  }
  if (lane == 0) {
    double v0 = -1e300, v1 = -1e300;
    int i0 = 0, i1 = 0;
#pragma unroll
    for (int e = 0; e < 8; ++e) {
      const double v = acc[e];
      if (v > v0)      { v1 = v0; i1 = i0; v0 = v; i0 = e; }
      else if (v > v1) { v1 = v; i1 = e; }
    }
    const float g0 = 1.0f / (1.0f + expf((float)(v1 - v0)));
    tok_idx[2 * t]     = i0;
    tok_idx[2 * t + 1] = i1;
    tok_gate[2 * t]     = g0;
    tok_gate[2 * t + 1] = 1.0f - g0;
  }
}

// ---------------- K2: count + padded offsets (single block) ----------------
__global__ void k_count(const int* __restrict__ tok_idx, int* __restrict__ hdr) {
  __shared__ int h[8];
  const int tid = threadIdx.x;
  if (tid < 8) h[tid] = 0;
  __syncthreads();
  int c[8] = {0, 0, 0, 0, 0, 0, 0, 0};
  for (int i = tid; i < 2 * T_TOK; i += 256) {
    const int e = tok_idx[i];
#pragma unroll
    for (int q = 0; q < 8; ++q) c[q] += (e == q) ? 1 : 0;
  }
#pragma unroll
  for (int q = 0; q < 8; ++q) {
#pragma unroll
    for (int off = 32; off > 0; off >>= 1) c[q] += __shfl_down(c[q], off);
  }
  if ((tid & 63) == 0) {
#pragma unroll
    for (int q = 0; q < 8; ++q) atomicAdd(&h[q], c[q]);
  }
  __syncthreads();
  if (tid == 0) {
    int off = 0;
#pragma unroll
    for (int e = 0; e < 8; ++e) {
      hdr[e] = h[e];
      hdr[8 + e] = 0;
      hdr[16 + e] = off;
      off += (h[e] + PADU - 1) & ~(PADU - 1);
    }
    hdr[24] = off;
    hdr[25] = off;
  }
}

// ---------------- K3: scatter (block-reserve; writes row gate too) ---------
__global__ void k_scatter(const int* __restrict__ tok_idx,
                          const float* __restrict__ tok_gate,
                          int* __restrict__ hdr,
                          int* __restrict__ bucket_tok,
                          float* __restrict__ row_gate,
                          int* __restrict__ rowmap) {
  __shared__ int lcnt[8], lbase[8];
  const int tid = threadIdx.x;
  const int i = blockIdx.x * 256 + tid;
  const int e = tok_idx[i];
  if (tid < 8) lcnt[tid] = 0;
  __syncthreads();
  const int pos = atomicAdd(&lcnt[e], 1);
  __syncthreads();
  if (tid < 8) lbase[tid] = atomicAdd(&hdr[8 + tid], lcnt[tid]);
  __syncthreads();
  const int r = hdr[16 + e] + lbase[e] + pos;
  bucket_tok[r] = i >> 1;
  row_gate[r] = tok_gate[i];   // real rows: sigmoid in (0,1), never 0.0f
  rowmap[i] = r;
}

// ---------------- K4: x fp32 -> bf16 ---------------------------------------
__global__ void k_cvt_x(const float* __restrict__ x, unsigned short* __restrict__ xb) {
  const int i = blockIdx.x * 256 + threadIdx.x;
  const float4 v = reinterpret_cast<const float4*>(x)[i];
  ushort4 h;
  h.x = f2bf(v.x); h.y = f2bf(v.y); h.z = f2bf(v.z); h.w = f2bf(v.w);
  reinterpret_cast<ushort4*>(xb)[i] = h;
}

// ---------------- K5: convert+transpose src[e][R][C] f32 -> dst[e][map(c)][R]
__global__ void k_cvtT(const float* __restrict__ src, unsigned short* __restrict__ dst,
                       int R, int C, int ilv) {
  const int e  = blockIdx.z;
  const int c0 = blockIdx.x * 64;
  const int r0 = blockIdx.y * 64;
  __shared__ unsigned short t[64][72];
  const int tid = threadIdx.x;
  const float* s = src + (size_t)e * R * C;
  unsigned short* d = dst + (size_t)e * R * C;
#pragma unroll
  for (int p = 0; p < 4; ++p) {
    const int idx = tid + p * 256;
    const int r  = idx >> 4;
    const int c4 = (idx & 15) << 2;
    const float4 v = *reinterpret_cast<const float4*>(s + (size_t)(r0 + r) * C + c0 + c4);
    t[c4 + 0][r] = f2bf(v.x); t[c4 + 1][r] = f2bf(v.y);
    t[c4 + 2][r] = f2bf(v.z); t[c4 + 3][r] = f2bf(v.w);
  }
  __syncthreads();
#pragma unroll
  for (int p = 0; p < 2; ++p) {
    const int idx = tid + p * 256;
    const int c  = idx >> 3;
    const int r8 = (idx & 7) << 3;
    u16x8 v;
#pragma unroll
    for (int i = 0; i < 8; ++i) v[i] = t[c][r8 + i];
    const int n = c0 + c;
    int row = n;
    if (ilv) {
      const int j = n & (FFN - 1);
      const int half = n >> 11;
      row = ((j >> 4) << 5) + (half << 4) + (j & 15);
    }
    *reinterpret_cast<u16x8*>(d + (size_t)row * R + r0 + r8) = v;
  }
}

// ---------------- K6: GEMM1 (256^2 8-phase)  act = (x@w1a)*silu(x@w1g) -----
__global__ __launch_bounds__(512, 2) void k_gemm1(
    const unsigned short* __restrict__ xb, const unsigned short* __restrict__ w1i,
    const int* __restrict__ bucket_tok, const int* __restrict__ hdr,
    unsigned short* __restrict__ act) {
  const int total = hdr[25];
  const int L    = blockIdx.y * 16 + blockIdx.x;
  const int xcd  = L & 7;
  const int slot = L >> 3;
  const int bx   = (xcd << 1) | (slot & 1);
  const int m0   = (slot >> 1) * 256;
  if (m0 >= total) return;
  int e = 0;
#pragma unroll
  for (int q = 1; q < 8; ++q) e += (m0 >= hdr[16 + q]) ? 1 : 0;
  const unsigned short* w1e = w1i + (size_t)e * 4096 * 1024;

  __shared__ __align__(16) char Lds[2 * 65536]; // per dbuf: A @0, B @32768

  const int tid  = threadIdx.x;
  const int lane = tid & 63;
  const int w    = tid >> 6;
  const int wm   = w >> 2;
  const int wn   = w & 3;
  const int lr   = lane & 15;
  const int qk16 = (lane >> 4) << 4;
  const int swz  = (lane & 7) << 4;
  const int kb0  = qk16 ^ swz;
  const int kb1  = (64 + qk16) ^ swz;

  const int r0 = w * 16 + (lane >> 3);
  const int cq = ((lane & 7) ^ (lane >> 3)) << 3;
  int aoff[2][2], boff[2][2];
#pragma unroll
  for (int h = 0; h < 2; ++h) {
    aoff[h][0] = bucket_tok[m0 + h * 128 + r0] * 1024 + cq;
    aoff[h][1] = bucket_tok[m0 + h * 128 + r0 + 8] * 1024 + cq;
    boff[h][0] = (bx * 256 + h * 128 + r0) * 1024 + cq;
    boff[h][1] = (bx * 256 + h * 128 + r0 + 8) * 1024 + cq;
  }
  const int ld0 = w * 2048 + lane * 16;

#define SA(dst, tt, h) do {                                                  \
    GLDS16(xb + aoff[h][0] + (tt) * 64, (dst) + (h) * 16384 + ld0);          \
    GLDS16(xb + aoff[h][1] + (tt) * 64, (dst) + (h) * 16384 + 1024 + ld0);   \
  } while (0)
#define SB(dst, tt, h) do {                                                  \
    GLDS16(w1e + boff[h][0] + (tt) * 64, (dst) + 32768 + (h) * 16384 + ld0); \
    GLDS16(w1e + boff[h][1] + (tt) * 64, (dst) + 32768 + (h) * 16384 + 1024 + ld0); \
  } while (0)

  f32x4 acc[8][4] = {};
  bf16x8 afq[4][2], bfr[4][2];

#define RD_A(M0) do {                                                        \
    _Pragma("unroll") for (int i = 0; i < 4; ++i) {                          \
      const int ra = wm * 128 + ((M0) + i) * 16 + lr;                        \
      afq[i][0] = *reinterpret_cast<const bf16x8*>(Ab + ra * 128 + kb0);     \
      afq[i][1] = *reinterpret_cast<const bf16x8*>(Ab + ra * 128 + kb1);     \
    } } while (0)
#define RD_B2(N0) do {                                                       \
    _Pragma("unroll") for (int i = 0; i < 2; ++i) {                          \
      const int rb = wn * 64 + ((N0) + i) * 16 + lr;                         \
      bfr[(N0) + i][0] = *reinterpret_cast<const bf16x8*>(Bb + rb * 128 + kb0); \
      bfr[(N0) + i][1] = *reinterpret_cast<const bf16x8*>(Bb + rb * 128 + kb1); \
    } } while (0)
#define QUAD(M0, N0) do {                                                    \
    __builtin_amdgcn_s_setprio(1);                                           \
    _Pragma("unroll") for (int mi = 0; mi < 4; ++mi)                         \
      _Pragma("unroll") for (int ni = 0; ni < 2; ++ni) {                     \
        acc[(M0) + mi][(N0) + ni] = __builtin_amdgcn_mfma_f32_16x16x32_bf16( \
            afq[mi][0], bfr[(N0) + ni][0], acc[(M0) + mi][(N0) + ni], 0, 0, 0); \
        acc[(M0) + mi][(N0) + ni] = __builtin_amdgcn_mfma_f32_16x16x32_bf16( \
            afq[mi][1], bfr[(N0) + ni][1], acc[(M0) + mi][(N0) + ni], 0, 0, 0); \
      }                                                                      \
    __builtin_amdgcn_s_setprio(0);                                           \
  } while (0)

  {
    char* D0 = Lds;
    char* D1 = Lds + 65536;
    SB(D0, 0, 0); SB(D0, 0, 1);
    SA(D0, 0, 0); SA(D0, 0, 1);
    SB(D1, 1, 0); SB(D1, 1, 1);
    SFENCE();
    VMW(4);
    BARRIER();
  }

  for (int t = 0; t < 16; ++t) {
    char* Ab = Lds + (t & 1) * 65536;
    char* Bb = Ab + 32768;
    char* Nb = Lds + ((t + 1) & 1) * 65536;
    RD_A(0); RD_B2(0);
    if (t < 15) SA(Nb, t + 1, 0);
    BARRIER(); LGKM0();
    QUAD(0, 0);
    BARRIER();
    RD_B2(2);
    if (t < 15) SA(Nb, t + 1, 1);
    BARRIER(); LGKM0();
    QUAD(0, 2);
    BARRIER();
    RD_A(4);
    if (t < 14) SB(Ab, t + 2, 0);
    BARRIER(); LGKM0();
    QUAD(4, 2);
    BARRIER();
    if (t < 14) SB(Ab, t + 2, 1);
    BARRIER();
    QUAD(4, 0);
    SFENCE();
    if (t < 14)      { VMW(4); }
    else if (t == 14) { VMW(0); }
    BARRIER();
  }
#undef SA
#undef SB
#undef RD_A
#undef RD_B2
#undef QUAD

  const int orow = (lane >> 4) << 2;
  const int baseCol = bx * 128 + wn * 32;
#pragma unroll
  for (int mi = 0; mi < 8; ++mi) {
#pragma unroll
    for (int p = 0; p < 2; ++p) {
      const f32x4 va = acc[mi][2 * p];
      const f32x4 vg = acc[mi][2 * p + 1];
#pragma unroll
      for (int r = 0; r < 4; ++r) {
        const float g = vg[r];
        const float v = va[r] * (g / (1.0f + expf(-g)));
        const int gm = m0 + wm * 128 + mi * 16 + orow + r;
        const int gc = baseCol + p * 16 + lr;
        act[(size_t)gm * FFN + gc] = f2bf(v);
      }
    }
  }
}

// ---------------- K7: GEMM2  out[tok] += g * (act @ w2[e]) -----------------
// R10 body; epilogue = gated fp32 atomicAdd into out (2 adds/element,
// commutative => deterministic). Pad rows have gate==0.0f and are skipped.
__global__ __launch_bounds__(512, 2) void k_gemm2(
    const unsigned short* __restrict__ act, const unsigned short* __restrict__ w2t,
    const int* __restrict__ hdr, const int* __restrict__ bucket_tok,
    const float* __restrict__ row_gate, float* __restrict__ out) {
  const int total = hdr[25];
  const int L  = blockIdx.y * 8 + blockIdx.x;
  const int m0 = (L >> 3) * 128;
  const int n0 = (L & 7) * 128;
  if (m0 >= total) return;
  int e = 0;
#pragma unroll
  for (int q = 1; q < 8; ++q) e += (m0 >= hdr[16 + q]) ? 1 : 0;
  const unsigned short* w2e = w2t + (size_t)e * 1024 * 2048;

  __shared__ __align__(16) char Lds[3 * 32768];

  const int tid  = threadIdx.x;
  const int lane = tid & 63;
  const int w    = tid >> 6;
  const int wrow = (w >> 2) * 64;
  const int wcol = (w & 3) * 32;
  const int lr   = lane & 15;
  const int qk16 = (lane >> 4) << 4;
  const int ldsw = w * 1024;

  const int srow = tid >> 3;
  const int cswz = (((tid & 7) ^ (srow & 7)) << 3);
  const int aoff0 = (m0 + srow) * FFN + cswz;
  const int boff0 = (n0 + srow) * FFN + cswz;

  f32x4 acc[4][2] = {};

#define G2_STAGE(base, kt) do {                                             \
    const unsigned short* as = act + (kt) * 64;                             \
    const unsigned short* ws = w2e + (kt) * 64;                             \
    GLDS16(as + aoff0,          Lds + (base) + ldsw);                       \
    GLDS16(as + aoff0 + 131072, Lds + (base) + 8192 + ldsw);                \
    GLDS16(ws + boff0,          Lds + (base) + 16384 + ldsw);               \
    GLDS16(ws + boff0 + 131072, Lds + (base) + 24576 + ldsw);               \
  } while (0)

  G2_STAGE(0, 0);
  G2_STAGE(32768, 1);
  SFENCE();
  asm volatile("s_waitcnt vmcnt(4)\n\ts_barrier" ::: "memory");
  SFENCE();

  int cur = 0, nxt2 = 2;
  for (int t = 0; t < 32; ++t) {
    const int pre = t + 2;
    if (pre < 32) {
      const int pb = ((cur + 2) >= 3 ? (cur - 1) : (cur + 2)) * 32768;
      G2_STAGE(pb, pre);
      SFENCE();
    }
    {
      const char* Ab = (const char*)Lds + cur * 32768;
      const char* Bb = Ab + 16384;
#pragma unroll
      for (int kk = 0; kk < 2; ++kk) {
        bf16x8 af[4], bv[2];
#pragma unroll
        for (int i = 0; i < 4; ++i) {
          const int ra = wrow + i * 16 + lr;
          af[i] = *reinterpret_cast<const bf16x8*>(Ab + ra * 128 + ((kk * 64 + qk16) ^ ((ra & 7) << 4)));
        }
#pragma unroll
        for (int i = 0; i < 2; ++i) {
          const int rb = wcol + i * 16 + lr;
          bv[i] = *reinterpret_cast<const bf16x8*>(Bb + rb * 128 + ((kk * 64 + qk16) ^ ((rb & 7) << 4)));
        }
        __builtin_amdgcn_s_setprio(1);
#pragma unroll
        for (int mi = 0; mi < 4; ++mi)
#pragma unroll
          for (int ni = 0; ni < 2; ++ni)
            acc[mi][ni] = __builtin_amdgcn_mfma_f32_16x16x32_bf16(af[mi], bv[ni], acc[mi][ni], 0, 0, 0);
        __builtin_amdgcn_s_setprio(0);
      }
    }
    SFENCE();
    if (pre < 32)      { asm volatile("s_waitcnt vmcnt(4)\n\ts_barrier" ::: "memory"); }
    else if (t + 1 < 32) { asm volatile("s_waitcnt vmcnt(0)\n\ts_barrier" ::: "memory"); }
    SFENCE();
    cur = (cur == 2) ? 0 : (cur + 1);
    nxt2 = (nxt2 == 2) ? 0 : (nxt2 + 1);
  }
#undef G2_STAGE

  // epilogue: gated atomic accumulate into out[token][col]
  const int orow = (lane >> 4) << 2;
#pragma unroll
  for (int mi = 0; mi < 4; ++mi)
#pragma unroll
    for (int r = 0; r < 4; ++r) {
      const int gm = m0 + wrow + mi * 16 + orow + r;
      const float g = row_gate[gm];
      if (g != 0.0f) {
        const int tok = bucket_tok[gm];
        float* orow_p = out + (size_t)tok * HID;
#pragma unroll
        for (int ni = 0; ni < 2; ++ni) {
          const int gc = n0 + wcol + ni * 16 + lr;
          atomicAdd(orow_p + gc, g * acc[mi][ni][r]);
        }
      }
    }
}

extern "C" void kernel_launch(void* const* d_in, const int* in_sizes, int n_in,
                              void* d_out, int out_size, void* d_ws, size_t ws_size,
                              hipStream_t stream) {
  const float* x  = (const float*)d_in[0]; // [8192][1024]
  const float* wr = (const float*)d_in[1]; // [1024][8]
  const float* w1 = (const float*)d_in[2]; // [8][1024][4096]
  const float* w2 = (const float*)d_in[3]; // [8][2048][1024]
  float* out = (float*)d_out;              // [8192][1024] fp32

  char* w = (char*)d_ws;
  int*   hdr        = (int*)w;
  int*   tok_idx    = (int*)(w + 1024);
  float* tok_gate   = (float*)(w + 1024 + 65536);
  int*   rowmap     = (int*)(w + 1024 + 2 * 65536);
  int*   bucket_tok = (int*)(w + 1024 + 3 * 65536);            // int[18432]
  float* row_gate   = (float*)(w + 1024 + 3 * 65536 + 73728);  // float[18432]
  const size_t R1 = 524288;
  unsigned short* xb  = (unsigned short*)(w + R1);
  unsigned short* w1i = (unsigned short*)(w + R1 + 16777216);
  unsigned short* w2t = (unsigned short*)(w + R1);             // overlay
  unsigned short* act = (unsigned short*)(w + R1 + 83886080);

  hipMemsetAsync(bucket_tok, 0, MAXPAD * sizeof(int), stream);   // pad rows -> token 0
  hipMemsetAsync(row_gate, 0, MAXPAD * sizeof(float), stream);   // pad rows -> gate 0
  hipMemsetAsync(out, 0, (size_t)T_TOK * HID * sizeof(float), stream);

  k_router<<<T_TOK / 8, 512, 0, stream>>>(x, wr, tok_idx, tok_gate);
  k_count<<<1, 256, 0, stream>>>(tok_idx, hdr);
  k_scatter<<<(2 * T_TOK) / 256, 256, 0, stream>>>(tok_idx, tok_gate, hdr,
                                                   bucket_tok, row_gate, rowmap);
  k_cvt_x<<<(T_TOK * HID / 4) / 256, 256, 0, stream>>>(x, xb);
  k_cvtT<<<dim3(4096 / 64, 1024 / 64, 8), 256, 0, stream>>>(w1, w1i, 1024, 4096, 1);
  k_gemm1<<<dim3(16, MTG1), 512, 0, stream>>>(xb, w1i, bucket_tok, hdr, act);
  k_cvtT<<<dim3(1024 / 64, 2048 / 64, 8), 256, 0, stream>>>(w2, w2t, 2048, 1024, 0);
  k_gemm2<<<dim3(8, MTG2), 512, 0, stream>>>(act, w2t, hdr, bucket_tok, row_gate, out);
}

// Round 12
// 389.897 us; speedup vs baseline: 1.1525x; 1.1525x over previous
//
#include <hip/hip_runtime.h>
#include <hip/hip_bf16.h>
#include <math.h>

// MoE MLP: T=8192 tokens, 8 experts, top-2, HID=1024, FFN=2048 (GLU).
// R12: revert of R11's atomic fusion -> exact R8 kernel (best verified,
// 388.2 us). Depth-3 counted-vmcnt pipelined GEMMs, fused swiglu via
// 16-interleaved w1 columns, XOR-swizzled LDS via pre-swizzled source.

#define T_TOK 8192
#define HID   1024
#define NEXP  8
#define FFN   2048
#define PADU  128
#define MAXPAD (2 * T_TOK + NEXP * PADU) /* 17408 */
#define MT1    (MAXPAD / 128)            /* 136 m-tiles */

typedef __attribute__((ext_vector_type(4))) float f32x4;
typedef __attribute__((ext_vector_type(8))) short bf16x8;
typedef __attribute__((ext_vector_type(8))) unsigned short u16x8;

static __device__ __forceinline__ unsigned short f2bf(float f) {
  unsigned int u = __float_as_uint(f);
  u += 0x7fffu + ((u >> 16) & 1u);
  return (unsigned short)(u >> 16);
}
static __device__ __forceinline__ float bf2f(unsigned short h) {
  return __uint_as_float(((unsigned int)h) << 16);
}

#define GLDS16(gsrc, ldst)                                                  \
  __builtin_amdgcn_global_load_lds(                                        \
      (const __attribute__((address_space(1))) void*)(gsrc),               \
      (__attribute__((address_space(3))) void*)(ldst), 16, 0, 0)

#define SCHED_FENCE() __builtin_amdgcn_sched_barrier(0)
// fused counted-wait + barrier: single asm stmt so nothing lands between
#define WAIT_BAR(n) asm volatile("s_waitcnt vmcnt(" #n ")\n\ts_barrier" ::: "memory")

// ---------------- K1: router (fp64 acc, LDS wr^T, no atomics) --------------
__global__ __launch_bounds__(512) void k_router(
    const float* __restrict__ x, const float* __restrict__ wr,
    int* __restrict__ tok_idx, float* __restrict__ tok_gate) {
  __shared__ float wrT[8][1024];
  const int tid = threadIdx.x;
#pragma unroll
  for (int p = 0; p < 4; ++p) {
    const int idx = tid + p * 512;
    const float4 v = reinterpret_cast<const float4*>(wr)[idx];
    const int f = idx * 4;
    wrT[(f + 0) & 7][(f + 0) >> 3] = v.x;
    wrT[(f + 1) & 7][(f + 1) >> 3] = v.y;
    wrT[(f + 2) & 7][(f + 2) >> 3] = v.z;
    wrT[(f + 3) & 7][(f + 3) >> 3] = v.w;
  }
  __syncthreads();

  const int lane = tid & 63;
  const int wid  = tid >> 6;
  const int t    = blockIdx.x * 8 + wid;
  const float* xr = x + (size_t)t * HID;

  double acc[8] = {};
#pragma unroll
  for (int j = 0; j < 16; ++j) {
    const int k = lane + j * 64;
    const double xv = (double)xr[k];
#pragma unroll
    for (int e = 0; e < 8; ++e) acc[e] += xv * (double)wrT[e][k];
  }
#pragma unroll
  for (int e = 0; e < 8; ++e) {
#pragma unroll
    for (int off = 32; off > 0; off >>= 1) acc[e] += __shfl_down(acc[e], off);
  }
  if (lane == 0) {
    double v0 = -1e300, v1 = -1e300;
    int i0 = 0, i1 = 0;
#pragma unroll
    for (int e = 0; e < 8; ++e) {
      const double v = acc[e];
      if (v > v0)      { v1 = v0; i1 = i0; v0 = v; i0 = e; }
      else if (v > v1) { v1 = v; i1 = e; }
    }
    const float g0 = 1.0f / (1.0f + expf((float)(v1 - v0)));
    tok_idx[2 * t]     = i0;
    tok_idx[2 * t + 1] = i1;
    tok_gate[2 * t]     = g0;
    tok_gate[2 * t + 1] = 1.0f - g0;
  }
}

// ---------------- K2: count + padded offsets (single block) ----------------
__global__ void k_count(const int* __restrict__ tok_idx, int* __restrict__ hdr) {
  __shared__ int h[8];
  const int tid = threadIdx.x;
  if (tid < 8) h[tid] = 0;
  __syncthreads();
  int c[8] = {0, 0, 0, 0, 0, 0, 0, 0};
  for (int i = tid; i < 2 * T_TOK; i += 256) {
    const int e = tok_idx[i];
#pragma unroll
    for (int q = 0; q < 8; ++q) c[q] += (e == q) ? 1 : 0;
  }
#pragma unroll
  for (int q = 0; q < 8; ++q) {
#pragma unroll
    for (int off = 32; off > 0; off >>= 1) c[q] += __shfl_down(c[q], off);
  }
  if ((tid & 63) == 0) {
#pragma unroll
    for (int q = 0; q < 8; ++q) atomicAdd(&h[q], c[q]);
  }
  __syncthreads();
  if (tid == 0) {
    int off = 0;
#pragma unroll
    for (int e = 0; e < 8; ++e) {
      hdr[e] = h[e];
      hdr[8 + e] = 0;
      hdr[16 + e] = off;
      off += (h[e] + PADU - 1) & ~(PADU - 1);
    }
    hdr[24] = off;
    hdr[25] = off;
  }
}

// ---------------- K3: scatter (block-reserve: 8 global atomics/block) ------
__global__ void k_scatter(const int* __restrict__ tok_idx, int* __restrict__ hdr,
                          int* __restrict__ bucket_tok, int* __restrict__ rowmap) {
  __shared__ int lcnt[8], lbase[8];
  const int tid = threadIdx.x;
  const int i = blockIdx.x * 256 + tid;
  const int e = tok_idx[i];
  if (tid < 8) lcnt[tid] = 0;
  __syncthreads();
  const int pos = atomicAdd(&lcnt[e], 1);
  __syncthreads();
  if (tid < 8) lbase[tid] = atomicAdd(&hdr[8 + tid], lcnt[tid]);
  __syncthreads();
  const int r = hdr[16 + e] + lbase[e] + pos;
  bucket_tok[r] = i >> 1;
  rowmap[i] = r;
}

// ---------------- K4: x fp32 -> bf16 ---------------------------------------
__global__ void k_cvt_x(const float* __restrict__ x, unsigned short* __restrict__ xb) {
  const int i = blockIdx.x * 256 + threadIdx.x;
  const float4 v = reinterpret_cast<const float4*>(x)[i];
  ushort4 h;
  h.x = f2bf(v.x); h.y = f2bf(v.y); h.z = f2bf(v.z); h.w = f2bf(v.w);
  reinterpret_cast<ushort4*>(xb)[i] = h;
}

// ---------------- K5: convert+transpose src[e][R][C] f32 -> dst[e][map(c)][R]
__global__ void k_cvtT(const float* __restrict__ src, unsigned short* __restrict__ dst,
                       int R, int C, int ilv) {
  const int e  = blockIdx.z;
  const int c0 = blockIdx.x * 64;
  const int r0 = blockIdx.y * 64;
  __shared__ unsigned short t[64][72];
  const int tid = threadIdx.x;
  const float* s = src + (size_t)e * R * C;
  unsigned short* d = dst + (size_t)e * R * C;
#pragma unroll
  for (int p = 0; p < 4; ++p) {
    const int idx = tid + p * 256;
    const int r  = idx >> 4;
    const int c4 = (idx & 15) << 2;
    const float4 v = *reinterpret_cast<const float4*>(s + (size_t)(r0 + r) * C + c0 + c4);
    t[c4 + 0][r] = f2bf(v.x); t[c4 + 1][r] = f2bf(v.y);
    t[c4 + 2][r] = f2bf(v.z); t[c4 + 3][r] = f2bf(v.w);
  }
  __syncthreads();
#pragma unroll
  for (int p = 0; p < 2; ++p) {
    const int idx = tid + p * 256;
    const int c  = idx >> 3;
    const int r8 = (idx & 7) << 3;
    u16x8 v;
#pragma unroll
    for (int i = 0; i < 8; ++i) v[i] = t[c][r8 + i];
    const int n = c0 + c;
    int row = n;
    if (ilv) {
      const int j = n & (FFN - 1);
      const int half = n >> 11;
      row = ((j >> 4) << 5) + (half << 4) + (j & 15);
    }
    *reinterpret_cast<u16x8*>(d + (size_t)row * R + r0 + r8) = v;
  }
}

// ---------------- K6: GEMM1  act = (x@w1a) * silu(x@w1g) -------------------
// BM=128 x BN=256(interleaved a/g), BK=64, 8 waves, wave out 64x64.
// Depth-3 pipeline: counted vmcnt(6), fused wait+barrier, sched fences.
__global__ __launch_bounds__(512, 2) void k_gemm1(
    const unsigned short* __restrict__ xb, const unsigned short* __restrict__ w1i,
    const int* __restrict__ bucket_tok, const int* __restrict__ hdr,
    unsigned short* __restrict__ act) {
  const int total = hdr[25];
  const int m0 = blockIdx.y * 128;
  if (m0 >= total) return;
  int e = 0;
#pragma unroll
  for (int q = 1; q < 8; ++q) e += (m0 >= hdr[16 + q]) ? 1 : 0;
  const int bx = blockIdx.x;
  const unsigned short* w1e = w1i + (size_t)e * 4096 * 1024;

  __shared__ __align__(16) char Lds[3 * 49152]; // 144 KB: 3 x (A 16K + B 32K)

  const int tid  = threadIdx.x;
  const int lane = tid & 63;
  const int w    = tid >> 6;
  const int wrow = (w >> 2) * 64;
  const int wcol = (w & 3) * 64;
  const int lr   = lane & 15;
  const int qk16 = (lane >> 4) << 4;
  const int ldsw = w * 1024;

  const int srow = tid >> 3;
  const int cswz = (((tid & 7) ^ (srow & 7)) << 3);
  const int aoffA0 = bucket_tok[m0 + srow] * 1024 + cswz;
  const int aoffA1 = bucket_tok[m0 + 64 + srow] * 1024 + cswz;
  const int boffB0 = (bx * 256 + srow) * 1024 + cswz;

  f32x4 acc[4][4] = {};

#define G1_STAGE(base, kt) do {                                             \
    const unsigned short* xs = xb + (kt) * 64;                              \
    const unsigned short* ws = w1e + (kt) * 64;                             \
    GLDS16(xs + aoffA0,           Lds + (base) + ldsw);                     \
    GLDS16(xs + aoffA1,           Lds + (base) + 8192 + ldsw);              \
    GLDS16(ws + boffB0,           Lds + (base) + 16384 + ldsw);             \
    GLDS16(ws + boffB0 + 65536,   Lds + (base) + 24576 + ldsw);             \
    GLDS16(ws + boffB0 + 131072,  Lds + (base) + 32768 + ldsw);             \
    GLDS16(ws + boffB0 + 196608,  Lds + (base) + 40960 + ldsw);             \
  } while (0)

  G1_STAGE(0, 0);
  G1_STAGE(49152, 1);
  SCHED_FENCE();
  WAIT_BAR(6);          // stage 0 landed (all waves)
  SCHED_FENCE();

  int cur = 0, nxt2 = 2; // buffer of stage t, buffer of stage t+2
  for (int t = 0; t < 16; ++t) {
    if (t + 2 < 16) {
      G1_STAGE(nxt2 * 49152, t + 2);
      SCHED_FENCE();    // pin: stage issue BEFORE compute & wait
    }
    {
      const char* Ab = (const char*)Lds + cur * 49152;
      const char* Bb = Ab + 16384;
#pragma unroll
      for (int kk = 0; kk < 2; ++kk) {
        bf16x8 af[4], bv[4];
#pragma unroll
        for (int i = 0; i < 4; ++i) {
          const int ra = wrow + i * 16 + lr;
          af[i] = *reinterpret_cast<const bf16x8*>(Ab + ra * 128 + ((kk * 64 + qk16) ^ ((ra & 7) << 4)));
          const int rb = wcol + i * 16 + lr;
          bv[i] = *reinterpret_cast<const bf16x8*>(Bb + rb * 128 + ((kk * 64 + qk16) ^ ((rb & 7) << 4)));
        }
        __builtin_amdgcn_s_setprio(1);
#pragma unroll
        for (int mi = 0; mi < 4; ++mi)
#pragma unroll
          for (int ni = 0; ni < 4; ++ni)
            acc[mi][ni] = __builtin_amdgcn_mfma_f32_16x16x32_bf16(af[mi], bv[ni], acc[mi][ni], 0, 0, 0);
        __builtin_amdgcn_s_setprio(0);
      }
    }
    SCHED_FENCE();      // pin: compute (incl. ds_reads) BEFORE the wait
    if (t + 2 < 16)      WAIT_BAR(6);  // stage t+1 landed; t+2 stays in flight
    else if (t + 1 < 16) WAIT_BAR(0);  // penultimate: drain last stage
    SCHED_FENCE();
    cur = (cur == 2) ? 0 : (cur + 1);
    nxt2 = (nxt2 == 2) ? 0 : (nxt2 + 1);
  }
#undef G1_STAGE

  // epilogue: frag ni even = a, odd = g (16-interleaved)
  const int orow = (lane >> 4) << 2;
  const int acb = bx * 128 + (wcol >> 1);
#pragma unroll
  for (int mi = 0; mi < 4; ++mi)
#pragma unroll
    for (int p = 0; p < 2; ++p) {
      const f32x4 va = acc[mi][2 * p];
      const f32x4 vg = acc[mi][2 * p + 1];
#pragma unroll
      for (int r = 0; r < 4; ++r) {
        const float g = vg[r];
        const float v = va[r] * (g / (1.0f + expf(-g)));
        const int gm = m0 + wrow + mi * 16 + orow + r;
        const int gc = acb + p * 16 + lr;
        act[(size_t)gm * FFN + gc] = f2bf(v);
      }
    }
}

// ---------------- K7: GEMM2  y = act @ w2[e] -------------------------------
// BM=128 x BN=128, BK=64, 8 waves, wave out 64x32. Depth-3, vmcnt(4).
__global__ __launch_bounds__(512, 2) void k_gemm2(
    const unsigned short* __restrict__ act, const unsigned short* __restrict__ w2t,
    const int* __restrict__ hdr, unsigned short* __restrict__ y) {
  const int total = hdr[25];
  const int m0 = blockIdx.y * 128;
  if (m0 >= total) return;
  int e = 0;
#pragma unroll
  for (int q = 1; q < 8; ++q) e += (m0 >= hdr[16 + q]) ? 1 : 0;
  const int n0 = blockIdx.x * 128;
  const unsigned short* w2e = w2t + (size_t)e * 1024 * 2048;

  __shared__ __align__(16) char Lds[3 * 32768]; // 96 KB: 3 x (A 16K + B 16K)

  const int tid  = threadIdx.x;
  const int lane = tid & 63;
  const int w    = tid >> 6;
  const int wrow = (w >> 2) * 64;
  const int wcol = (w & 3) * 32;
  const int lr   = lane & 15;
  const int qk16 = (lane >> 4) << 4;
  const int ldsw = w * 1024;

  const int srow = tid >> 3;
  const int cswz = (((tid & 7) ^ (srow & 7)) << 3);
  const int aoff0 = (m0 + srow) * FFN + cswz;
  const int boff0 = (n0 + srow) * FFN + cswz;

  f32x4 acc[4][2] = {};

#define G2_STAGE(base, kt) do {                                             \
    const unsigned short* as = act + (kt) * 64;                             \
    const unsigned short* ws = w2e + (kt) * 64;                             \
    GLDS16(as + aoff0,          Lds + (base) + ldsw);                       \
    GLDS16(as + aoff0 + 131072, Lds + (base) + 8192 + ldsw);                \
    GLDS16(ws + boff0,          Lds + (base) + 16384 + ldsw);               \
    GLDS16(ws + boff0 + 131072, Lds + (base) + 24576 + ldsw);               \
  } while (0)

  G2_STAGE(0, 0);
  G2_STAGE(32768, 1);
  SCHED_FENCE();
  WAIT_BAR(4);
  SCHED_FENCE();

  int cur = 0, nxt2 = 2;
  for (int t = 0; t < 32; ++t) {
    if (t + 2 < 32) {
      G2_STAGE(nxt2 * 32768, t + 2);
      SCHED_FENCE();
    }
    {
      const char* Ab = (const char*)Lds + cur * 32768;
      const char* Bb = Ab + 16384;
#pragma unroll
      for (int kk = 0; kk < 2; ++kk) {
        bf16x8 af[4], bv[2];
#pragma unroll
        for (int i = 0; i < 4; ++i) {
          const int ra = wrow + i * 16 + lr;
          af[i] = *reinterpret_cast<const bf16x8*>(Ab + ra * 128 + ((kk * 64 + qk16) ^ ((ra & 7) << 4)));
        }
#pragma unroll
        for (int i = 0; i < 2; ++i) {
          const int rb = wcol + i * 16 + lr;
          bv[i] = *reinterpret_cast<const bf16x8*>(Bb + rb * 128 + ((kk * 64 + qk16) ^ ((rb & 7) << 4)));
        }
        __builtin_amdgcn_s_setprio(1);
#pragma unroll
        for (int mi = 0; mi < 4; ++mi)
#pragma unroll
          for (int ni = 0; ni < 2; ++ni)
            acc[mi][ni] = __builtin_amdgcn_mfma_f32_16x16x32_bf16(af[mi], bv[ni], acc[mi][ni], 0, 0, 0);
        __builtin_amdgcn_s_setprio(0);
      }
    }
    SCHED_FENCE();
    if (t + 2 < 32)      WAIT_BAR(4);
    else if (t + 1 < 32) WAIT_BAR(0);
    SCHED_FENCE();
    cur = (cur == 2) ? 0 : (cur + 1);
    nxt2 = (nxt2 == 2) ? 0 : (nxt2 + 1);
  }
#undef G2_STAGE

  const int orow = (lane >> 4) << 2;
#pragma unroll
  for (int mi = 0; mi < 4; ++mi)
#pragma unroll
    for (int ni = 0; ni < 2; ++ni)
#pragma unroll
      for (int r = 0; r < 4; ++r) {
        const int gm = m0 + wrow + mi * 16 + orow + r;
        const int gc = n0 + wcol + ni * 16 + lr;
        y[(size_t)gm * HID + gc] = f2bf(acc[mi][ni][r]);
      }
}

// ---------------- K8: combine  out[t] = g0*y[r0] + g1*y[r1] ----------------
__global__ void k_combine(const unsigned short* __restrict__ y,
                          const int* __restrict__ rowmap,
                          const float* __restrict__ tok_gate,
                          float* __restrict__ out) {
  const int t = blockIdx.x;
  const int c = threadIdx.x << 2;
  const int r0 = rowmap[2 * t], r1 = rowmap[2 * t + 1];
  const float g0 = tok_gate[2 * t], g1 = tok_gate[2 * t + 1];
  const ushort4 a = *reinterpret_cast<const ushort4*>(y + (size_t)r0 * HID + c);
  const ushort4 b = *reinterpret_cast<const ushort4*>(y + (size_t)r1 * HID + c);
  float4 o;
  o.x = g0 * bf2f(a.x) + g1 * bf2f(b.x);
  o.y = g0 * bf2f(a.y) + g1 * bf2f(b.y);
  o.z = g0 * bf2f(a.z) + g1 * bf2f(b.z);
  o.w = g0 * bf2f(a.w) + g1 * bf2f(b.w);
  *reinterpret_cast<float4*>(out + (size_t)t * HID + c) = o;
}

extern "C" void kernel_launch(void* const* d_in, const int* in_sizes, int n_in,
                              void* d_out, int out_size, void* d_ws, size_t ws_size,
                              hipStream_t stream) {
  const float* x  = (const float*)d_in[0]; // [8192][1024]
  const float* wr = (const float*)d_in[1]; // [1024][8]
  const float* w1 = (const float*)d_in[2]; // [8][1024][4096]
  const float* w2 = (const float*)d_in[3]; // [8][2048][1024]
  float* out = (float*)d_out;              // [8192][1024] fp32

  char* w = (char*)d_ws;
  int*   hdr        = (int*)w;
  int*   tok_idx    = (int*)(w + 1024);
  float* tok_gate   = (float*)(w + 1024 + 65536);
  int*   rowmap     = (int*)(w + 1024 + 2 * 65536);
  int*   bucket_tok = (int*)(w + 1024 + 3 * 65536);
  const size_t R1 = 524288;
  unsigned short* xb  = (unsigned short*)(w + R1);
  unsigned short* w1i = (unsigned short*)(w + R1 + 16777216);
  unsigned short* w2t = (unsigned short*)(w + R1);             // overlay
  unsigned short* yb  = (unsigned short*)(w + R1 + 33554432);  // overlay
  unsigned short* act = (unsigned short*)(w + R1 + 83886080);

  hipMemsetAsync(bucket_tok, 0, MAXPAD * sizeof(int), stream); // pad rows -> token 0

  k_router<<<T_TOK / 8, 512, 0, stream>>>(x, wr, tok_idx, tok_gate);
  k_count<<<1, 256, 0, stream>>>(tok_idx, hdr);
  k_scatter<<<(2 * T_TOK) / 256, 256, 0, stream>>>(tok_idx, hdr, bucket_tok, rowmap);
  k_cvt_x<<<(T_TOK * HID / 4) / 256, 256, 0, stream>>>(x, xb);
  k_cvtT<<<dim3(4096 / 64, 1024 / 64, 8), 256, 0, stream>>>(w1, w1i, 1024, 4096, 1);
  k_gemm1<<<dim3(16, MT1), 512, 0, stream>>>(xb, w1i, bucket_tok, hdr, act);
  k_cvtT<<<dim3(1024 / 64, 2048 / 64, 8), 256, 0, stream>>>(w2, w2t, 2048, 1024, 0);
  k_gemm2<<<dim3(8, MT1), 512, 0, stream>>>(act, w2t, hdr, yb);
  k_combine<<<T_TOK, 256, 0, stream>>>(yb, rowmap, tok_gate, out);
}